// Round 3
// baseline (121.732 us; speedup 1.0000x reference)
//
#include <hip/hip_runtime.h>

// Problem constants (B=16, L=96, D=512)
#define BB 16
#define LL 96
#define DD 512
// Workspace layout (floats):
//   a_ws:    [1536][512]  (X @ W1[:D] + b1)
//   c_ws:    [1536][512]  (X @ W1[D:])
//   logits:  [16][96][96]
#define AC_ELEMS (1536 * 512)
#define LOGIT_ELEMS (BB * LL * LL)

// ---------------------------------------------------------------------------
// Kernel 1: f32 SGEMM computing a and c.
// Grid: x = 1536/64 = 24 row tiles; y = 16 (low 3 bits: col tile of 8, bit 3: part)
// Block: 256 threads. Tile 64x64, BK=32. Per-thread 4x4 micro-tile.
// ---------------------------------------------------------------------------
__global__ __launch_bounds__(256) void gemm_ac(const float* __restrict__ X,
                                               const float* __restrict__ W1,
                                               const float* __restrict__ b1,
                                               float* __restrict__ a_ws,
                                               float* __restrict__ c_ws) {
  // stride 68 on XsT: write banks = (16c+4i+row)%32-ish -> <=2-way; rows stay 16B aligned
  __shared__ float XsT[32][68];  // [k][row], transposed for b128 row-fragment reads
  __shared__ float Ws[32][64];   // [k][col]

  const int t = threadIdx.x;
  const int m0 = blockIdx.x * 64;
  const int part = blockIdx.y >> 3;          // 0 -> a (+b1), 1 -> c
  const int n0 = (blockIdx.y & 7) * 64;      // within the 512-wide half
  const float* __restrict__ Wb = W1 + (size_t)part * (512 * 512);  // W1[(part*512+d)*512+h]

  float acc[4][4] = {};

  const int r0 = (t >> 4) << 2;   // 0..60 (row fragment)
  const int c0 = (t & 15) << 2;   // 0..60 (col fragment)
  const int xrow = t >> 3;        // 0..31
  const int xcol = (t & 7) << 2;  // 0..28 (k offset)
  const int wkr = t >> 4;         // 0..15
  const int wc = (t & 15) << 2;   // 0..60

  for (int k0 = 0; k0 < 512; k0 += 32) {
    // global loads first (latency overlaps the barrier)
    const float4 xv0 = *(const float4*)(X + (size_t)(m0 + xrow) * 512 + k0 + xcol);
    const float4 xv1 = *(const float4*)(X + (size_t)(m0 + xrow + 32) * 512 + k0 + xcol);
    const float4 wv0 = *(const float4*)(Wb + (size_t)(k0 + wkr) * 512 + n0 + wc);
    const float4 wv1 = *(const float4*)(Wb + (size_t)(k0 + wkr + 16) * 512 + n0 + wc);
    __syncthreads();  // previous iteration's LDS reads complete
    XsT[xcol + 0][xrow] = xv0.x;
    XsT[xcol + 1][xrow] = xv0.y;
    XsT[xcol + 2][xrow] = xv0.z;
    XsT[xcol + 3][xrow] = xv0.w;
    XsT[xcol + 0][xrow + 32] = xv1.x;
    XsT[xcol + 1][xrow + 32] = xv1.y;
    XsT[xcol + 2][xrow + 32] = xv1.z;
    XsT[xcol + 3][xrow + 32] = xv1.w;
    *(float4*)&Ws[wkr][wc] = wv0;
    *(float4*)&Ws[wkr + 16][wc] = wv1;
    __syncthreads();

#pragma unroll
    for (int kk = 0; kk < 32; ++kk) {
      const float4 av = *(const float4*)&XsT[kk][r0];
      const float4 bv = *(const float4*)&Ws[kk][c0];
      acc[0][0] = fmaf(av.x, bv.x, acc[0][0]);
      acc[0][1] = fmaf(av.x, bv.y, acc[0][1]);
      acc[0][2] = fmaf(av.x, bv.z, acc[0][2]);
      acc[0][3] = fmaf(av.x, bv.w, acc[0][3]);
      acc[1][0] = fmaf(av.y, bv.x, acc[1][0]);
      acc[1][1] = fmaf(av.y, bv.y, acc[1][1]);
      acc[1][2] = fmaf(av.y, bv.z, acc[1][2]);
      acc[1][3] = fmaf(av.y, bv.w, acc[1][3]);
      acc[2][0] = fmaf(av.z, bv.x, acc[2][0]);
      acc[2][1] = fmaf(av.z, bv.y, acc[2][1]);
      acc[2][2] = fmaf(av.z, bv.z, acc[2][2]);
      acc[2][3] = fmaf(av.z, bv.w, acc[2][3]);
      acc[3][0] = fmaf(av.w, bv.x, acc[3][0]);
      acc[3][1] = fmaf(av.w, bv.y, acc[3][1]);
      acc[3][2] = fmaf(av.w, bv.z, acc[3][2]);
      acc[3][3] = fmaf(av.w, bv.w, acc[3][3]);
    }
  }

  float* __restrict__ outp = (part == 0) ? a_ws : c_ws;
  float4 bias;
  if (part == 0)
    bias = *(const float4*)(b1 + n0 + c0);
  else
    bias = make_float4(0.f, 0.f, 0.f, 0.f);
#pragma unroll
  for (int ri = 0; ri < 4; ++ri) {
    float4 v;
    v.x = acc[ri][0] + bias.x;
    v.y = acc[ri][1] + bias.y;
    v.z = acc[ri][2] + bias.z;
    v.w = acc[ri][3] + bias.w;
    *(float4*)(outp + (size_t)(m0 + r0 + ri) * 512 + n0 + c0) = v;
  }
}

// ---------------------------------------------------------------------------
// Kernel 2: pairwise logits.  logits[b][i][j] = sum_h lrelu(a[i,h]+c[j,h])*w2[h]
// (b2/TAU dropped: constant shift cancels in log_softmax.)
// Grid: (16, 6, 6); block 256. Each block: 16 i-rows x 16 j-rows; 1 logit/thread.
// ---------------------------------------------------------------------------
__global__ __launch_bounds__(256) void coh_kernel(const float* __restrict__ a_ws,
                                                  const float* __restrict__ c_ws,
                                                  const float* __restrict__ W2,
                                                  float* __restrict__ logits) {
  __shared__ float As[16][516];  // stride 516 -> bank rotation by 4 per row
  __shared__ float Cs[16][516];
  __shared__ float w2s[512];

  const int b = blockIdx.x;
  const int it = blockIdx.y;
  const int jt = blockIdx.z;
  const int t = threadIdx.x;

  const float* __restrict__ abase = a_ws + ((size_t)b * 96 + it * 16) * 512;
  const float* __restrict__ cbase = c_ws + ((size_t)b * 96 + jt * 16) * 512;

#pragma unroll
  for (int p = 0; p < 8; ++p) {
    const int idx = p * 256 + t;        // float4 index 0..2047
    const int row = idx >> 7;           // 0..15
    const int col = (idx & 127) << 2;   // 0..508
    *(float4*)&As[row][col] = *(const float4*)(abase + (size_t)row * 512 + col);
    *(float4*)&Cs[row][col] = *(const float4*)(cbase + (size_t)row * 512 + col);
  }
  if (t < 128) *(float4*)&w2s[t << 2] = *(const float4*)(W2 + (t << 2));
  __syncthreads();

  const int il = t >> 4;
  const int jl = t & 15;
  float acc = 0.f;
#pragma unroll 8
  for (int h = 0; h < 512; h += 4) {
    const float4 av = *(const float4*)&As[il][h];
    const float4 cv = *(const float4*)&Cs[jl][h];
    const float4 wv = *(const float4*)&w2s[h];
    float x;
    x = av.x + cv.x; acc = fmaf(fmaxf(x, 0.1f * x), wv.x, acc);
    x = av.y + cv.y; acc = fmaf(fmaxf(x, 0.1f * x), wv.y, acc);
    x = av.z + cv.z; acc = fmaf(fmaxf(x, 0.1f * x), wv.z, acc);
    x = av.w + cv.w; acc = fmaf(fmaxf(x, 0.1f * x), wv.w, acc);
  }
  logits[((size_t)b * 96 + it * 16 + il) * 96 + jt * 16 + jl] = acc;
}

// ---------------------------------------------------------------------------
// Kernel 3: softmax + cross-entropy with exact argmax/first-match semantics.
// Grid: 96 blocks (16 b x 6 row-groups); block 256 = 4 waves; wave handles 4 rows.
// targets[i] = first j with order[j]==order[i]+1 else 0; row 'last' (first-argmax
// of order) is ignore_index. loss = sum(lse - logit[t]) / (16*95).
// ---------------------------------------------------------------------------
__global__ __launch_bounds__(256) void loss_kernel(const float* __restrict__ logits,
                                                   const int* __restrict__ order,
                                                   float* __restrict__ out) {
  __shared__ float wsum[4];
  const int b = blockIdx.x / 6;
  const int rg = (blockIdx.x % 6) * 16;
  const int t = threadIdx.x;
  const int w = t >> 6;
  const int lane = t & 63;

  const int* __restrict__ ob = order + b * 96;
  const int ov = ob[lane];                                    // j = lane (0..63)
  const int ov2 = (lane < 32) ? ob[64 + lane] : (int)0x80000000;  // j = 64+lane

  // last = first index of max(order[b,:])
  int mo = (ov > ov2) ? ov : ov2;
#pragma unroll
  for (int d = 1; d < 64; d <<= 1) {
    const int o = __shfl_xor(mo, d);
    mo = (o > mo) ? o : mo;
  }
  const unsigned long long lm1 = __ballot(ov == mo);
  const unsigned long long lm2 = __ballot(lane < 32 && ov2 == mo);
  const int last = lm1 ? (__ffsll(lm1) - 1) : (64 + __ffsll(lm2) - 1);

  float lsum = 0.f;
  for (int r = rg + w; r < rg + 16; r += 4) {
    const float* __restrict__ lr = logits + ((size_t)b * 96 + r) * 96;
    const float l1 = lr[lane];
    const float l2 = (lane < 32) ? lr[64 + lane] : -1e30f;
    float m = fmaxf(l1, l2);
#pragma unroll
    for (int d = 1; d < 64; d <<= 1) m = fmaxf(m, __shfl_xor(m, d));
    float s = __expf(l1 - m) + ((lane < 32) ? __expf(l2 - m) : 0.f);
#pragma unroll
    for (int d = 1; d < 64; d <<= 1) s += __shfl_xor(s, d);
    const float lse = m + __logf(s);

    if (r != last) {
      const int oi = ob[r];
      const unsigned long long c1 = __ballot(ov == oi + 1);
      const unsigned long long c2 = __ballot(lane < 32 && ov2 == oi + 1);
      const int tj = c1 ? (__ffsll(c1) - 1) : (c2 ? (64 + __ffsll(c2) - 1) : 0);
      lsum += lse - lr[tj];
    }
  }
  if (lane == 0) wsum[w] = lsum;
  __syncthreads();
  if (t == 0) {
    atomicAdd(out, (wsum[0] + wsum[1] + wsum[2] + wsum[3]) * (1.0f / (16.0f * 95.0f)));
  }
}

// ---------------------------------------------------------------------------
extern "C" void kernel_launch(void* const* d_in, const int* in_sizes, int n_in,
                              void* d_out, int out_size, void* d_ws, size_t ws_size,
                              hipStream_t stream) {
  const float* X = (const float*)d_in[0];     // (16,96,512)
  const float* W1 = (const float*)d_in[1];    // (1024,512)
  const float* b1 = (const float*)d_in[2];    // (512,)
  const float* W2 = (const float*)d_in[3];    // (512,1)
  // d_in[4] = b2 (cancels in log_softmax), d_in[5] = mask (all ones)
  const int* order = (const int*)d_in[6];     // (16,96)
  float* out = (float*)d_out;

  float* ws = (float*)d_ws;
  float* a_ws = ws;
  float* c_ws = ws + AC_ELEMS;
  float* logits = ws + 2 * AC_ELEMS;
  // total ws use: (2*1536*512 + 16*96*96)*4 = ~6.9 MB

  hipMemsetAsync(out, 0, sizeof(float), stream);
  gemm_ac<<<dim3(24, 16), 256, 0, stream>>>(X, W1, b1, a_ws, c_ws);
  coh_kernel<<<dim3(16, 6, 6), 256, 0, stream>>>(a_ws, c_ws, W2, logits);
  loss_kernel<<<96, 256, 0, stream>>>(logits, order, out);
}